// Round 15
// baseline (110.067 us; speedup 1.0000x reference)
//
#include <hip/hip_runtime.h>

typedef unsigned short u16t;
typedef unsigned int   u32t;
typedef __bf16 bf16x8 __attribute__((ext_vector_type(8)));
typedef float  f32x4  __attribute__((ext_vector_type(4)));

#define NB   64
#define DIN  1024
#define DOUT 256
#define EPS  1e-4f   // LR*LR
#define KP   68      // LDS row stride in u16 (34 dw == 2 mod 32; proven pattern)

#define OUT_STATE (NB*DIN*DOUT)
#define OUT_LL    (OUT_STATE + 1)
#define OUT_RR    (OUT_LL + NB*DIN)

__device__ __forceinline__ u16t f2b(float x) {
    u32t u = __builtin_bit_cast(u32t, x);
    u += 0x7FFFu + ((u >> 16) & 1u);          // RTNE
    return (u16t)(u >> 16);
}
__device__ __forceinline__ float b2f(u16t h) {
    return __builtin_bit_cast(float, ((u32t)h) << 16);
}
__device__ __forceinline__ u32t pk(u16t lo, u16t hi) {
    return (u32t)lo | ((u32t)hi << 16);
}
__device__ __forceinline__ bf16x8 ld_frag(const u16t* p) {
    uint2 lo = *(const uint2*)(p);
    uint2 hi = *(const uint2*)(p + 4);
    union { uint4 u; bf16x8 v; } x;
    x.u = make_uint4(lo.x, lo.y, hi.x, hi.y);
    return x.v;
}
__device__ __forceinline__ void st8(u16t* p, u32t a, u32t b) {
    *(uint2*)(p) = make_uint2(a, b);
}

// ============================================================
// K1 (k_prep): stats only, no LDS (R5-proven shape).
//   row moments -> ll (out), AS = ll^-1/4, col partials CP (128 slots/n).
// grid 2048 = (32 chunks x 64 n), block 256 (4 waves x 8 rows).
// ============================================================
__global__ __launch_bounds__(256) void k_prep(
    const float* __restrict__ grad, const float* __restrict__ L0,
    float* __restrict__ out, float* __restrict__ AS, float* __restrict__ CP)
{
    const int bid = blockIdx.x;
    const int n = bid & 63;
    const int chunk = bid >> 6;                 // 0..31
    const int wave = threadIdx.x >> 6, lane = threadIdx.x & 63;
    const float* gb = grad + ((size_t)n << 18);

    float4 cacc = {0.f, 0.f, 0.f, 0.f};
    const int i0 = chunk * 32 + wave * 8;
    #pragma unroll
    for (int r = 0; r < 8; ++r) {
        const int i = i0 + r;
        const float4 v = *(const float4*)(gb + (size_t)i * 256 + lane * 4);
        float s = v.x*v.x + v.y*v.y + v.z*v.z + v.w*v.w;
        cacc.x += v.x*v.x; cacc.y += v.y*v.y; cacc.z += v.z*v.z; cacc.w += v.w*v.w;
        #pragma unroll
        for (int off = 32; off; off >>= 1) s += __shfl_xor(s, off);
        const float l0 = L0[n * DIN + i];
        const float ll = fmaxf(l0, 0.5f * l0 + s * (0.5f / DOUT));
        if (lane == 0) {
            out[OUT_LL + n * DIN + i] = ll;
            AS[n * DIN + i] = rsqrtf(sqrtf(ll));
        }
    }
    const int slot = chunk * 4 + wave;          // 0..127
    *(float4*)(CP + ((size_t)(n * 128 + slot)) * 256 + lane * 4) = cacc;
}

// ============================================================
// K2: reduce 128 col partials -> rr (out), BS = rr^-1/4 ; copy state
// ============================================================
__global__ __launch_bounds__(256) void k_cols(
    const float* __restrict__ R0, const float* __restrict__ state,
    float* __restrict__ out, float* __restrict__ BS, const float* __restrict__ CP)
{
    const int n = blockIdx.x, o = threadIdx.x;
    const float* cp = CP + (size_t)n * 128 * 256 + o;
    float s = 0.f;
    #pragma unroll 8
    for (int k = 0; k < 128; ++k) s += cp[k * 256];
    const float r0 = R0[n * DOUT + o];
    const float rr = fmaxf(r0, 0.5f * r0 + s * (0.5f / DIN));
    out[OUT_RR + n * DOUT + o] = rr;
    BS[n * DOUT + o] = rsqrtf(sqrtf(rr));
    if (n == 0 && o == 0) out[OUT_STATE] = state[0];
}

// ============================================================
// G1 (k_T): split-K partial GEMM.
//   TTP[kq][n][o][p] = bf16( sum_{i in K-quarter kq} (a_i*grad[i][o]) * M[i][p] )
// tile 128o x 64p, per-block K = 256 (4 chunks of 64).
// grid 2048 = (4 kq x 8 tiles x 64 n) -> ~6 blocks/CU (LDS-capped).
// Transpose staging: coalesced dword column reads, paired-row packed
// u32 LDS writes (24 writes/chunk/thread).
// ============================================================
__global__ __launch_bounds__(256, 4) void k_T(
    const float* __restrict__ grad, const float* __restrict__ M,
    const float* __restrict__ AS, u16t* __restrict__ TTP)
{
    __shared__ u16t sA[128 * KP];   // [o][i]
    __shared__ u16t sB[64 * KP];    // [p][i]
    const int bid = blockIdx.x;
    const int n = bid & 63;
    const int tile = (bid >> 6) & 7;            // 2 o-tiles x 4 p-tiles
    const int kq = bid >> 9;                    // 0..3
    const int o0 = (tile & 1) * 128, p0 = (tile >> 1) * 64;
    const int t = threadIdx.x, lane = t & 63, w = t >> 6;
    const int wr = w >> 1, wc = w & 1, t16 = lane & 15, g4 = lane >> 4;
    const float* Gn = grad + ((size_t)n << 18);
    const float* Mn = M + ((size_t)n << 18);
    const float* An = AS + n * DIN;
    f32x4 acc[4][2] = {};

    for (int ch = 0; ch < 4; ++ch) {
        const int ib = kq * 256 + ch * 64;
        __syncthreads();
        #pragma unroll
        for (int r = 0; r < 8; ++r) {
            const int il0 = w * 16 + 2 * r;     // even local row pair
            const int ig0 = ib + il0;
            const float a0 = An[ig0], a1 = An[ig0 + 1];
            const float* g0 = Gn + (size_t)ig0 * 256 + o0;
            const float* g1 = g0 + 256;
            const float* m0 = Mn + (size_t)ig0 * 256 + p0;
            const float* m1 = m0 + 256;
            *(u32t*)&sA[(size_t)lane * KP + il0] =
                pk(f2b(g0[lane] * a0),      f2b(g1[lane] * a1));
            *(u32t*)&sA[(size_t)(lane + 64) * KP + il0] =
                pk(f2b(g0[lane + 64] * a0), f2b(g1[lane + 64] * a1));
            *(u32t*)&sB[(size_t)lane * KP + il0] =
                pk(f2b(m0[lane]),           f2b(m1[lane]));
        }
        __syncthreads();
        #pragma unroll
        for (int kb = 0; kb < 2; ++kb) {
            const int ko = kb * 32 + g4 * 8;
            bf16x8 fa[4], fb[2];
            #pragma unroll
            for (int fm = 0; fm < 4; ++fm)
                fa[fm] = ld_frag(sA + (wr*64 + fm*16 + t16) * KP + ko);
            #pragma unroll
            for (int fn = 0; fn < 2; ++fn)
                fb[fn] = ld_frag(sB + (wc*32 + fn*16 + t16) * KP + ko);
            #pragma unroll
            for (int fm = 0; fm < 4; ++fm)
                #pragma unroll
                for (int fn = 0; fn < 2; ++fn)
                    acc[fm][fn] = __builtin_amdgcn_mfma_f32_16x16x32_bf16(fa[fm], fb[fn], acc[fm][fn], 0, 0, 0);
        }
    }
    u16t* TTq = TTP + ((size_t)kq << 22) + ((size_t)n << 16);
    #pragma unroll
    for (int fm = 0; fm < 4; ++fm)
        #pragma unroll
        for (int fn = 0; fn < 2; ++fn) {
            const int p = p0 + wc*32 + fn*16 + t16;
            #pragma unroll
            for (int r = 0; r < 4; ++r) {
                const int o = o0 + wr*64 + fm*16 + g4*4 + r;
                TTq[o * 256 + p] = f2b(acc[fm][fn][r]);
            }
        }
}

// ============================================================
// K3 (k_red): TT[n][o][p] = bf16( b[o] * sum_q TTP[q][n][o][p] )
// Fully coalesced, BW-bound (~40MB). grid 2048, block 256, 8 u16/thread.
// ============================================================
__global__ __launch_bounds__(256) void k_red(
    const u16t* __restrict__ TTP, const float* __restrict__ BS,
    u16t* __restrict__ TT)
{
    const size_t idx8 = ((size_t)blockIdx.x * 256 + threadIdx.x) * 8;
    const int n = (int)(idx8 >> 16);
    const int o = (int)((idx8 >> 8) & 255);
    const float bo = BS[n * DOUT + o];
    uint4 v0 = *(const uint4*)(TTP + ((size_t)0 << 22) + idx8);
    uint4 v1 = *(const uint4*)(TTP + ((size_t)1 << 22) + idx8);
    uint4 v2 = *(const uint4*)(TTP + ((size_t)2 << 22) + idx8);
    uint4 v3 = *(const uint4*)(TTP + ((size_t)3 << 22) + idx8);
    const u16t* a = (const u16t*)&v0;
    const u16t* b = (const u16t*)&v1;
    const u16t* c = (const u16t*)&v2;
    const u16t* d = (const u16t*)&v3;
    u16t r[8];
    #pragma unroll
    for (int e = 0; e < 8; ++e)
        r[e] = f2b((b2f(a[e]) + b2f(b[e]) + b2f(c[e]) + b2f(d[e])) * bo);
    const u32t* rw = (const u32t*)r;
    *(uint4*)(TT + idx8) = make_uint4(rw[0], rw[1], rw[2], rw[3]);
}

// ============================================================
// G2 (k_fuse): Mnew[i][o] = M[i][o] + EPS*( sum_p M[i][p]*TT[o][p]
//                                           - b_o * a_i * grad[i][o] )
// a_i re-derived from ll output (staged per block).
// tile 128i x 128o, K=256 (4 chunks). grid 1024 = (16 tiles x 64 n).
// ============================================================
__global__ __launch_bounds__(256, 3) void k_fuse(
    const float* __restrict__ M, const float* __restrict__ grad,
    const float* __restrict__ BS, const u16t* __restrict__ TT,
    float* __restrict__ out)
{
    __shared__ u16t sA[128 * KP];   // [i][p]
    __shared__ u16t sB[128 * KP];   // [o][p]
    __shared__ float sa_[128];      // a_i for this i-tile
    const int bid = blockIdx.x;
    const int n = bid & 63;
    const int tile = bid >> 6;                  // 0..15: 8 i-tiles x 2 o-tiles
    const int i0 = (tile & 7) * 128, o0 = (tile >> 3) * 128;
    const int t = threadIdx.x, lane = t & 63, w = t >> 6;
    const int wr = w >> 1, wc = w & 1, t16 = lane & 15, g4 = lane >> 4;
    const float* Mn = M + ((size_t)n << 18);
    const float* Gr = grad + ((size_t)n << 18);
    const u16t* TTn = TT + ((size_t)n << 16);
    if (t < 128) {
        const float ll = out[OUT_LL + n * DIN + i0 + t];
        sa_[t] = rsqrtf(sqrtf(ll));
    }
    float4 rMa[8];
    uint4  rTb[4];
    f32x4 acc[4][4] = {};

#define FU_LOAD(ch) { const int pb_ = (ch) * 64; \
    _Pragma("unroll") for (int j = 0; j < 8; ++j) { \
        const int s = j * 256 + t, row = s >> 4, c4 = (s & 15) * 4; \
        rMa[j] = *(const float4*)(Mn + (size_t)(i0 + row) * 256 + pb_ + c4); } \
    _Pragma("unroll") for (int j = 0; j < 4; ++j) { \
        const int s = j * 256 + t, row = s >> 3, c8 = (s & 7) * 8; \
        rTb[j] = *(const uint4*)(TTn + (size_t)(o0 + row) * 256 + pb_ + c8); } }

    FU_LOAD(0);
    for (int ch = 0; ch < 4; ++ch) {
        __syncthreads();
        #pragma unroll
        for (int j = 0; j < 8; ++j) {
            const int s = j * 256 + t, row = s >> 4, c4 = (s & 15) * 4;
            const float4 v = rMa[j];
            ushort4 h = { f2b(v.x), f2b(v.y), f2b(v.z), f2b(v.w) };
            *(ushort4*)(sA + row * KP + c4) = h;
        }
        #pragma unroll
        for (int j = 0; j < 4; ++j) {
            const int s = j * 256 + t, row = s >> 3, c8 = (s & 7) * 8;
            st8(sB + row * KP + c8,     rTb[j].x, rTb[j].y);
            st8(sB + row * KP + c8 + 4, rTb[j].z, rTb[j].w);
        }
        __syncthreads();
        if (ch < 3) FU_LOAD(ch + 1);
        #pragma unroll
        for (int kb = 0; kb < 2; ++kb) {
            const int ko = kb * 32 + g4 * 8;
            bf16x8 fa[4], fb[4];
            #pragma unroll
            for (int fm = 0; fm < 4; ++fm)
                fa[fm] = ld_frag(sA + (wr*64 + fm*16 + t16) * KP + ko);
            #pragma unroll
            for (int fn = 0; fn < 4; ++fn)
                fb[fn] = ld_frag(sB + (wc*64 + fn*16 + t16) * KP + ko);
            #pragma unroll
            for (int fm = 0; fm < 4; ++fm)
                #pragma unroll
                for (int fn = 0; fn < 4; ++fn)
                    acc[fm][fn] = __builtin_amdgcn_mfma_f32_16x16x32_bf16(fa[fm], fb[fn], acc[fm][fn], 0, 0, 0);
        }
    }
    const float* bs = BS + n * DOUT;
    float* outn = out + ((size_t)n << 18);
    #pragma unroll
    for (int fm = 0; fm < 4; ++fm)
        #pragma unroll
        for (int fn = 0; fn < 4; ++fn) {
            const int o = o0 + wc*64 + fn*16 + t16;
            const float bo = bs[o];
            #pragma unroll
            for (int r = 0; r < 4; ++r) {
                const int il = wr*64 + fm*16 + g4*4 + r;
                const int i = i0 + il;
                const size_t idx = (size_t)i * 256 + o;
                outn[idx] = Mn[idx] + EPS * (acc[fm][fn][r] - bo * sa_[il] * Gr[idx]);
            }
        }
}

extern "C" void kernel_launch(void* const* d_in, const int* in_sizes, int n_in,
                              void* d_out, int out_size, void* d_ws, size_t ws_size,
                              hipStream_t stream) {
    const float* grad  = (const float*)d_in[0];
    const float* M     = (const float*)d_in[1];
    const float* state = (const float*)d_in[2];
    const float* L0    = (const float*)d_in[3];
    const float* R0    = (const float*)d_in[4];
    float* out = (float*)d_out;
    char* wsb = (char*)d_ws;

    // region map (~49.5 MB):
    u16t*  TT  = (u16t*)(wsb);                          // [0,8MB)    TT[n][o][p]
    u16t*  TTP = (u16t*)(wsb + ((size_t)8 << 20));      // [8,40MB)   TTP[4][n][o][p]
    float* CP  = (float*)(wsb + ((size_t)40 << 20));    // [40,48MB)  CP[n][128][256]
    float* AS  = (float*)(wsb + ((size_t)48 << 20));    // [48,48.25) AS[n][1024]
    float* BS  = (float*)(wsb + ((size_t)49 << 20));    // 64KB

    k_prep <<<2048, 256, 0, stream>>>(grad, L0, out, AS, CP);
    k_cols <<<64,   256, 0, stream>>>(R0, state, out, BS, CP);
    k_T    <<<2048, 256, 0, stream>>>(grad, M, AS, TTP);
    k_red  <<<2048, 256, 0, stream>>>(TTP, BS, TT);
    k_fuse <<<1024, 256, 0, stream>>>(M, grad, BS, TT, out);
}